// Round 1
// baseline (566.500 us; speedup 1.0000x reference)
//
#include <hip/hip_runtime.h>
#include <stdint.h>

#define L_SEQ 1024
#define NHEAD 32
#define NPREV 28
#define HDIM  64
#define HID   2048
#define NPROJ 2560  // 2048 q + 256 k + 256 v

typedef __bf16 bf16_t;
typedef bf16_t bf16x8 __attribute__((ext_vector_type(8)));
typedef float  f32x4  __attribute__((ext_vector_type(4)));

__device__ __forceinline__ ushort f2bf(float x) {
    union { float f; uint32_t u; } v; v.f = x;
    uint32_t r = v.u + 0x7fffu + ((v.u >> 16) & 1u);
    return (ushort)(r >> 16);
}
__device__ __forceinline__ float bf2f(ushort u) {
    union { uint32_t u; float f; } v; v.u = ((uint32_t)u) << 16; return v.f;
}
// 8 packed bf16 (uint4) -> 8 floats
__device__ __forceinline__ void cvt8(float* dst, uint4 u) {
    union { uint32_t u; float f; } t;
    t.u = u.x << 16;         dst[0] = t.f;
    t.u = u.x & 0xffff0000u; dst[1] = t.f;
    t.u = u.y << 16;         dst[2] = t.f;
    t.u = u.y & 0xffff0000u; dst[3] = t.f;
    t.u = u.z << 16;         dst[4] = t.f;
    t.u = u.z & 0xffff0000u; dst[5] = t.f;
    t.u = u.w << 16;         dst[6] = t.f;
    t.u = u.w & 0xffff0000u; dst[7] = t.f;
}

// ---------------- fp32 -> bf16 conversion ----------------
__global__ void cvt_f32_bf16(const float* __restrict__ in, ushort* __restrict__ out, int n4) {
    int i = blockIdx.x * blockDim.x + threadIdx.x;
    if (i < n4) {
        float4 v = ((const float4*)in)[i];
        ushort4 o;
        o.x = f2bf(v.x); o.y = f2bf(v.y); o.z = f2bf(v.z); o.w = f2bf(v.w);
        ((ushort4*)out)[i] = o;
    }
}

// ---------------- bf16 GEMM: C[M,N] = A[M,K] * B[N,K]^T ----------------
// 128x128 tile, 4 waves in 2x2, each wave 64x64 = 4x4 MFMA tiles (m93 pattern).
template <bool OUT_BF16>
__global__ __launch_bounds__(256, 2) void gemm_bt(const ushort* __restrict__ A,
                                                  const ushort* __restrict__ B,
                                                  void* __restrict__ C,
                                                  int M, int N, int K) {
    __shared__ __align__(16) ushort Ash[128 * 32];
    __shared__ __align__(16) ushort Bsh[128 * 32];
    const int tid  = threadIdx.x;
    const int lane = tid & 63;
    const int wave = tid >> 6;
    const int quad = lane >> 4;
    const int l16  = lane & 15;
    const int m0 = blockIdx.y * 128;
    const int n0 = blockIdx.x * 128;
    const int wm = (wave >> 1) * 64;
    const int wn = (wave & 1) * 64;

    const int lrow = tid >> 2;        // 0..63
    const int lcol = (tid & 3) * 8;   // 0,8,16,24

    f32x4 acc[4][4] = {};

    const ushort* Ag = A + (long)m0 * K;
    const ushort* Bg = B + (long)n0 * K;

    for (int k0 = 0; k0 < K; k0 += 32) {
        uint4 a0 = *(const uint4*)(Ag + (long)lrow * K + k0 + lcol);
        uint4 a1 = *(const uint4*)(Ag + (long)(lrow + 64) * K + k0 + lcol);
        uint4 b0 = *(const uint4*)(Bg + (long)lrow * K + k0 + lcol);
        uint4 b1 = *(const uint4*)(Bg + (long)(lrow + 64) * K + k0 + lcol);
        __syncthreads();
        *(uint4*)(Ash + lrow * 32 + lcol)        = a0;
        *(uint4*)(Ash + (lrow + 64) * 32 + lcol) = a1;
        *(uint4*)(Bsh + lrow * 32 + lcol)        = b0;
        *(uint4*)(Bsh + (lrow + 64) * 32 + lcol) = b1;
        __syncthreads();
        bf16x8 af[4], bf[4];
#pragma unroll
        for (int i = 0; i < 4; i++) {
            af[i] = *(const bf16x8*)(Ash + (wm + i * 16 + l16) * 32 + quad * 8);
            bf[i] = *(const bf16x8*)(Bsh + (wn + i * 16 + l16) * 32 + quad * 8);
        }
#pragma unroll
        for (int mi = 0; mi < 4; mi++)
#pragma unroll
            for (int ni = 0; ni < 4; ni++)
                acc[mi][ni] = __builtin_amdgcn_mfma_f32_16x16x32_bf16(af[mi], bf[ni], acc[mi][ni], 0, 0, 0);
    }
#pragma unroll
    for (int mi = 0; mi < 4; mi++)
#pragma unroll
        for (int ni = 0; ni < 4; ni++)
#pragma unroll
            for (int r = 0; r < 4; r++) {
                int m = m0 + wm + mi * 16 + quad * 4 + r;
                int n = n0 + wn + ni * 16 + l16;
                float v = acc[mi][ni][r];
                if (OUT_BF16) ((ushort*)C)[(long)m * N + n] = f2bf(v);
                else          ((float*)C)[(long)m * N + n]  = v;
            }
}

// ---------------- prep: DeCAN gather + RoPE + scale fold ----------------
// proj: bf16 [B*L, 2560] ; outputs Qr/Kr/Vf bf16 [B,32,L,64]
__global__ void prep_qkv(const ushort* __restrict__ proj,
                         const float* __restrict__ prev_k,
                         const float* __restrict__ prev_v,
                         const float* __restrict__ cosb,
                         const float* __restrict__ sinb,
                         ushort* __restrict__ Qr, ushort* __restrict__ Kr,
                         ushort* __restrict__ Vf) {
    int idx = blockIdx.x * 256 + threadIdx.x;  // [0, 2*32*1024*64)
    int d = idx & 63;
    int l = (idx >> 6) & 1023;
    int h = (idx >> 16) & 31;
    int b = idx >> 21;
    float c = cosb[l * 64 + d], s = sinb[l * 64 + d];
    long prow = ((long)b * L_SEQ + l) * NPROJ;
    // Q
    float xq  = bf2f(proj[prow + h * 64 + d]);
    float xq2 = bf2f(proj[prow + h * 64 + (d ^ 32)]);
    float rq = (d < 32) ? -xq2 : xq2;
    Qr[idx] = f2bf((xq * c + rq * s) * 0.125f);
    // K
    float k1, k2;
    if (h < NPREV) {
        const float* pk = prev_k + (((long)b * NPREV + h) * L_SEQ + l) * 64;
        k1 = pk[d]; k2 = pk[d ^ 32];
    } else {
        const ushort* pk = proj + prow + HID + (h - NPREV) * 64;
        k1 = bf2f(pk[d]); k2 = bf2f(pk[d ^ 32]);
    }
    float rk = (d < 32) ? -k2 : k2;
    Kr[idx] = f2bf(k1 * c + rk * s);
    // V
    float vv;
    if (h < NPREV) vv = prev_v[(((long)b * NPREV + h) * L_SEQ + l) * 64 + d];
    else           vv = bf2f(proj[prow + HID + 256 + (h - NPREV) * 64 + d]);
    Vf[idx] = f2bf(vv);
}

// ---------------- flash-style vector attention ----------------
// grid (L/64, B*32). Block: 64 q-rows. kv tiles of 64. Online softmax.
// Thread t: rows {2*(t>>3), +1}; score cols {t&7 + 8*jj}; PV dims [(t&7)*8, +8)
#define KST 68
#define SST 66
#define QST 72
__global__ __launch_bounds__(256, 2) void attn_fwd(const ushort* __restrict__ Qr,
                                                   const ushort* __restrict__ Kr,
                                                   const ushort* __restrict__ Vf,
                                                   ushort* __restrict__ Oa) {
    __shared__ __align__(16) ushort Qsh[64 * QST];
    __shared__ __align__(16) float  Ksh[64 * KST];
    __shared__ __align__(16) float  Vsh[64 * 64];
    __shared__ __align__(16) float  Ssh[64 * SST];

    const int tid = threadIdx.x;
    const int bh  = blockIdx.y;
    const int q0  = blockIdx.x * 64;
    const long base = (long)bh * (L_SEQ * HDIM);

    const int lr = tid >> 2;
    const int lc = (tid & 3) << 4;
    {   // stage Q tile (bf16 copy)
        const ushort* g = Qr + base + (long)(q0 + lr) * HDIM + lc;
        uint4 u0 = *(const uint4*)g;
        uint4 u1 = *(const uint4*)(g + 8);
        *(uint4*)(Qsh + lr * QST + lc)     = u0;
        *(uint4*)(Qsh + lr * QST + lc + 8) = u1;
    }

    const int rp = tid >> 3;
    const int r0 = rp << 1;
    const int jb = tid & 7;
    const int db8 = jb << 3;

    float m0 = -1e30f, m1 = -1e30f, l0 = 0.f, l1 = 0.f;
    float acc0[8] = {}, acc1[8] = {};

    for (int kv0 = 0; kv0 <= q0; kv0 += 64) {
        __syncthreads();
        {   // stage K,V (bf16 -> fp32 LDS)
            const ushort* gk = Kr + base + (long)(kv0 + lr) * HDIM + lc;
            uint4 u0 = *(const uint4*)gk;
            uint4 u1 = *(const uint4*)(gk + 8);
            cvt8(Ksh + lr * KST + lc, u0);
            cvt8(Ksh + lr * KST + lc + 8, u1);
            const ushort* gv = Vf + base + (long)(kv0 + lr) * HDIM + lc;
            uint4 w0 = *(const uint4*)gv;
            uint4 w1 = *(const uint4*)(gv + 8);
            cvt8(Vsh + lr * 64 + lc, w0);
            cvt8(Vsh + lr * 64 + lc + 8, w1);
        }
        __syncthreads();

        // scores
        float s0[8] = {}, s1[8] = {};
        for (int kk = 0; kk < 64; kk += 8) {
            uint4 qa = *(const uint4*)(Qsh + r0 * QST + kk);
            uint4 qb = *(const uint4*)(Qsh + (r0 + 1) * QST + kk);
            float qaf[8], qbf[8];
            cvt8(qaf, qa); cvt8(qbf, qb);
#pragma unroll
            for (int jj = 0; jj < 8; jj++) {
                const float* kr = Ksh + (jb + (jj << 3)) * KST + kk;
                float4 kA = *(const float4*)kr;
                float4 kB = *(const float4*)(kr + 4);
                s0[jj] += qaf[0]*kA.x + qaf[1]*kA.y + qaf[2]*kA.z + qaf[3]*kA.w
                        + qaf[4]*kB.x + qaf[5]*kB.y + qaf[6]*kB.z + qaf[7]*kB.w;
                s1[jj] += qbf[0]*kA.x + qbf[1]*kA.y + qbf[2]*kA.z + qbf[3]*kA.w
                        + qbf[4]*kB.x + qbf[5]*kB.y + qbf[6]*kB.z + qbf[7]*kB.w;
            }
        }
        if (kv0 == q0) {  // diagonal causal mask
#pragma unroll
            for (int jj = 0; jj < 8; jj++) {
                int col = jb + (jj << 3);
                if (col > r0)     s0[jj] = -1e30f;
                if (col > r0 + 1) s1[jj] = -1e30f;
            }
        }
        // row max across own 8 + the 8 lanes sharing the row
        float rm0 = s0[0], rm1 = s1[0];
#pragma unroll
        for (int jj = 1; jj < 8; jj++) { rm0 = fmaxf(rm0, s0[jj]); rm1 = fmaxf(rm1, s1[jj]); }
        rm0 = fmaxf(rm0, __shfl_xor(rm0, 1)); rm0 = fmaxf(rm0, __shfl_xor(rm0, 2)); rm0 = fmaxf(rm0, __shfl_xor(rm0, 4));
        rm1 = fmaxf(rm1, __shfl_xor(rm1, 1)); rm1 = fmaxf(rm1, __shfl_xor(rm1, 2)); rm1 = fmaxf(rm1, __shfl_xor(rm1, 4));
        float nm0 = fmaxf(m0, rm0), nm1 = fmaxf(m1, rm1);
        float al0 = __expf(m0 - nm0), al1 = __expf(m1 - nm1);
        float p0[8], p1[8], ps0 = 0.f, ps1 = 0.f;
#pragma unroll
        for (int jj = 0; jj < 8; jj++) {
            p0[jj] = __expf(s0[jj] - nm0); ps0 += p0[jj];
            p1[jj] = __expf(s1[jj] - nm1); ps1 += p1[jj];
        }
        ps0 += __shfl_xor(ps0, 1); ps0 += __shfl_xor(ps0, 2); ps0 += __shfl_xor(ps0, 4);
        ps1 += __shfl_xor(ps1, 1); ps1 += __shfl_xor(ps1, 2); ps1 += __shfl_xor(ps1, 4);
        m0 = nm0; m1 = nm1;
        l0 = l0 * al0 + ps0; l1 = l1 * al1 + ps1;
#pragma unroll
        for (int d = 0; d < 8; d++) { acc0[d] *= al0; acc1[d] *= al1; }
#pragma unroll
        for (int jj = 0; jj < 8; jj++) {
            Ssh[r0 * SST + jb + (jj << 3)]       = p0[jj];
            Ssh[(r0 + 1) * SST + jb + (jj << 3)] = p1[jj];
        }
        __syncthreads();
        // PV
#pragma unroll 4
        for (int j = 0; j < 64; j++) {
            float pa = Ssh[r0 * SST + j];
            float pb = Ssh[(r0 + 1) * SST + j];
            const float* vr = Vsh + (j << 6) + db8;
            float4 vA = *(const float4*)vr;
            float4 vB = *(const float4*)(vr + 4);
            acc0[0] += pa*vA.x; acc0[1] += pa*vA.y; acc0[2] += pa*vA.z; acc0[3] += pa*vA.w;
            acc0[4] += pa*vB.x; acc0[5] += pa*vB.y; acc0[6] += pa*vB.z; acc0[7] += pa*vB.w;
            acc1[0] += pb*vA.x; acc1[1] += pb*vA.y; acc1[2] += pb*vA.z; acc1[3] += pb*vA.w;
            acc1[4] += pb*vB.x; acc1[5] += pb*vB.y; acc1[6] += pb*vB.z; acc1[7] += pb*vB.w;
        }
    }
    // epilogue: write [b, l, h*64+d] bf16 for out-projection GEMM
    float i0 = 1.f / l0, i1 = 1.f / l1;
    ushort o0[8], o1[8];
#pragma unroll
    for (int d = 0; d < 8; d++) { o0[d] = f2bf(acc0[d] * i0); o1[d] = f2bf(acc1[d] * i1); }
    int b = bh >> 5, h = bh & 31;
    ushort* O0 = Oa + (long)(b * L_SEQ + q0 + r0) * HID + h * 64 + db8;
    *(uint4*)O0          = *(uint4*)o0;
    *(uint4*)(O0 + HID)  = *(uint4*)o1;
}

// ---------------- host launch ----------------
extern "C" void kernel_launch(void* const* d_in, const int* in_sizes, int n_in,
                              void* d_out, int out_size, void* d_ws, size_t ws_size,
                              hipStream_t stream) {
    const float* hs     = (const float*)d_in[0];
    const float* prev_k = (const float*)d_in[1];
    const float* prev_v = (const float*)d_in[2];
    const float* Wq     = (const float*)d_in[3];
    const float* Wk     = (const float*)d_in[4];
    const float* Wv     = (const float*)d_in[5];
    const float* Wo     = (const float*)d_in[6];
    const float* cosb   = (const float*)d_in[7];
    const float* sinb   = (const float*)d_in[8];
    float* out = (float*)d_out;

    ushort* hs_bf   = (ushort*)d_ws;                 // 2048*2048
    ushort* wqkv_bf = hs_bf + 2048L * 2048;          // 2560*2048
    ushort* wo_bf   = wqkv_bf + 2560L * 2048;        // 2048*2048
    ushort* proj    = wo_bf + 2048L * 2048;          // 2048*2560
    ushort* Qr      = proj + 2048L * 2560;           // 2*32*1024*64
    ushort* Kr      = Qr + 4194304;
    ushort* Vf      = Kr + 4194304;
    ushort* Oa      = Vf + 4194304;                  // 2048*2048
    // total ws: ~71.3 MB

    cvt_f32_bf16<<<4096, 256, 0, stream>>>(hs, hs_bf, 1048576);
    cvt_f32_bf16<<<4096, 256, 0, stream>>>(Wq, wqkv_bf, 1048576);
    cvt_f32_bf16<<<512, 256, 0, stream>>>(Wk, wqkv_bf + 2048L * 2048, 131072);
    cvt_f32_bf16<<<512, 256, 0, stream>>>(Wv, wqkv_bf + 2304L * 2048, 131072);
    cvt_f32_bf16<<<4096, 256, 0, stream>>>(Wo, wo_bf, 1048576);

    gemm_bt<true><<<dim3(20, 16), 256, 0, stream>>>(hs_bf, wqkv_bf, proj, 2048, 2560, 2048);
    prep_qkv<<<16384, 256, 0, stream>>>(proj, prev_k, prev_v, cosb, sinb, Qr, Kr, Vf);
    attn_fwd<<<dim3(16, 64), 256, 0, stream>>>(Qr, Kr, Vf, Oa);
    gemm_bt<false><<<dim3(16, 16), 256, 0, stream>>>(Oa, wo_bf, out, 2048, 2048, 2048);
}

// Round 2
// 307.569 us; speedup vs baseline: 1.8419x; 1.8419x over previous
//
#include <hip/hip_runtime.h>
#include <stdint.h>

#define L_SEQ 1024
#define NHEAD 32
#define NPREV 28
#define HDIM  64
#define HID   2048
#define NPROJ 2560  // 2048 q + 256 k + 256 v

typedef __bf16 bf16_t;
typedef bf16_t bf16x8 __attribute__((ext_vector_type(8)));
typedef float  f32x4  __attribute__((ext_vector_type(4)));

__device__ __forceinline__ ushort f2bf(float x) {
    union { float f; uint32_t u; } v; v.f = x;
    uint32_t r = v.u + 0x7fffu + ((v.u >> 16) & 1u);
    return (ushort)(r >> 16);
}
__device__ __forceinline__ float bf2f(ushort u) {
    union { uint32_t u; float f; } v; v.u = ((uint32_t)u) << 16; return v.f;
}

#define GLB(p) ((const __attribute__((address_space(1))) void*)(p))
#define LDS(p) ((__attribute__((address_space(3))) void*)(p))

// ---------------- fp32 -> bf16 conversion ----------------
__global__ void cvt_f32_bf16(const float* __restrict__ in, ushort* __restrict__ out, int n4) {
    int i = blockIdx.x * blockDim.x + threadIdx.x;
    if (i < n4) {
        float4 v = ((const float4*)in)[i];
        ushort4 o;
        o.x = f2bf(v.x); o.y = f2bf(v.y); o.z = f2bf(v.z); o.w = f2bf(v.w);
        ((ushort4*)out)[i] = o;
    }
}

// ---------------- bf16 GEMM: C[M,N] = A[M,K] * B[N,K]^T ----------------
// 128x128 tile, 4 waves 2x2, global_load_lds width-16 staging (m97 pattern).
template <bool OUT_BF16>
__global__ __launch_bounds__(256, 2) void gemm_bt(const ushort* __restrict__ A,
                                                  const ushort* __restrict__ B,
                                                  void* __restrict__ C,
                                                  int M, int N, int K) {
    __shared__ __align__(16) ushort Ash[128 * 32];
    __shared__ __align__(16) ushort Bsh[128 * 32];
    const int tid  = threadIdx.x;
    const int lane = tid & 63;
    const int wave = tid >> 6;
    const int quad = lane >> 4;
    const int l16  = lane & 15;
    const int m0 = blockIdx.y * 128;
    const int n0 = blockIdx.x * 128;
    const int wm = (wave >> 1) * 64;
    const int wn = (wave & 1) * 64;

    const int lrow = tid >> 2;        // 0..63
    const int lcol = (tid & 3) * 8;   // 0,8,16,24

    f32x4 acc[4][4] = {};

    // per-lane global addresses; lds dest = wave-uniform base + lane*16B
    const ushort* Ag = A + (long)(m0 + lrow) * K + lcol;
    const ushort* Bg = B + (long)(n0 + lrow) * K + lcol;
    ushort* lA0 = Ash + wave * 512;
    ushort* lA1 = Ash + 2048 + wave * 512;
    ushort* lB0 = Bsh + wave * 512;
    ushort* lB1 = Bsh + 2048 + wave * 512;

    for (int k0 = 0; k0 < K; k0 += 32) {
        __syncthreads();
        __builtin_amdgcn_global_load_lds(GLB(Ag + k0),            LDS(lA0), 16, 0, 0);
        __builtin_amdgcn_global_load_lds(GLB(Ag + 64L * K + k0),  LDS(lA1), 16, 0, 0);
        __builtin_amdgcn_global_load_lds(GLB(Bg + k0),            LDS(lB0), 16, 0, 0);
        __builtin_amdgcn_global_load_lds(GLB(Bg + 64L * K + k0),  LDS(lB1), 16, 0, 0);
        __syncthreads();
        bf16x8 af[4], bf[4];
#pragma unroll
        for (int i = 0; i < 4; i++) {
            af[i] = *(const bf16x8*)(Ash + (wm + i * 16 + l16) * 32 + quad * 8);
            bf[i] = *(const bf16x8*)(Bsh + (wn + i * 16 + l16) * 32 + quad * 8);
        }
#pragma unroll
        for (int mi = 0; mi < 4; mi++)
#pragma unroll
            for (int ni = 0; ni < 4; ni++)
                acc[mi][ni] = __builtin_amdgcn_mfma_f32_16x16x32_bf16(af[mi], bf[ni], acc[mi][ni], 0, 0, 0);
    }
#pragma unroll
    for (int mi = 0; mi < 4; mi++)
#pragma unroll
        for (int ni = 0; ni < 4; ni++)
#pragma unroll
            for (int r = 0; r < 4; r++) {
                int m = m0 + wm + mi * 16 + quad * 4 + r;
                int n = n0 + wn + ni * 16 + l16;
                float v = acc[mi][ni][r];
                if (OUT_BF16) ((ushort*)C)[(long)m * N + n] = f2bf(v);
                else          ((float*)C)[(long)m * N + n]  = v;
            }
}

// ---------------- prep: DeCAN gather + RoPE + scale fold ----------------
__global__ void prep_qkv(const ushort* __restrict__ proj,
                         const float* __restrict__ prev_k,
                         const float* __restrict__ prev_v,
                         const float* __restrict__ cosb,
                         const float* __restrict__ sinb,
                         ushort* __restrict__ Qr, ushort* __restrict__ Kr,
                         ushort* __restrict__ Vf) {
    int idx = blockIdx.x * 256 + threadIdx.x;  // [0, 2*32*1024*64)
    int d = idx & 63;
    int l = (idx >> 6) & 1023;
    int h = (idx >> 16) & 31;
    int b = idx >> 21;
    float c = cosb[l * 64 + d], s = sinb[l * 64 + d];
    long prow = ((long)b * L_SEQ + l) * NPROJ;
    // Q (scale 1/sqrt(64) folded)
    float xq  = bf2f(proj[prow + h * 64 + d]);
    float xq2 = bf2f(proj[prow + h * 64 + (d ^ 32)]);
    float rq = (d < 32) ? -xq2 : xq2;
    Qr[idx] = f2bf((xq * c + rq * s) * 0.125f);
    // K
    float k1, k2;
    if (h < NPREV) {
        const float* pk = prev_k + (((long)b * NPREV + h) * L_SEQ + l) * 64;
        k1 = pk[d]; k2 = pk[d ^ 32];
    } else {
        const ushort* pk = proj + prow + HID + (h - NPREV) * 64;
        k1 = bf2f(pk[d]); k2 = bf2f(pk[d ^ 32]);
    }
    float rk = (d < 32) ? -k2 : k2;
    Kr[idx] = f2bf(k1 * c + rk * s);
    // V
    float vv;
    if (h < NPREV) vv = prev_v[(((long)b * NPREV + h) * L_SEQ + l) * 64 + d];
    else           vv = bf2f(proj[prow + HID + 256 + (h - NPREV) * 64 + d]);
    Vf[idx] = f2bf(vv);
}

// ---------------- V transpose: [bh][l][d] -> [bh][d][l] ----------------
__global__ void vtrans(const ushort* __restrict__ Vf, ushort* __restrict__ Vt) {
    __shared__ ushort T[64 * 65];
    const int tid = threadIdx.x;
    const int bh = blockIdx.y;
    const int l0 = blockIdx.x * 64;
    const long base = (long)bh * (L_SEQ * HDIM);
    const int r = tid >> 2;
    const int c0 = (tid & 3) * 16;
    const ushort* g = Vf + base + (long)(l0 + r) * HDIM + c0;
    uint4 a = *(const uint4*)g;
    uint4 b2 = *(const uint4*)(g + 8);
    ushort tmp[16];
    *(uint4*)tmp = a;
    *(uint4*)(tmp + 8) = b2;
#pragma unroll
    for (int i = 0; i < 16; i++) T[(c0 + i) * 65 + r] = tmp[i];
    __syncthreads();
    ushort out[16];
#pragma unroll
    for (int j = 0; j < 16; j++) out[j] = T[r * 65 + c0 + j];
    ushort* og = Vt + base + (long)r * L_SEQ + l0 + c0;
    *(uint4*)og = *(uint4*)out;
    *(uint4*)(og + 8) = *(uint4*)(out + 8);
}

// ---------------- MFMA flash attention ----------------
// grid (16 qtiles reversed, 64 bh), 4 waves; each wave: 16 q-rows.
// QK^T: A=Q(global frag), B=K(LDS). Softmax on C-layout (row=quad*4+r, col=nt*16+l16).
// P -> per-wave LDS -> A-frag; PV: B=V^T(LDS). O C-layout matches S rows => in-lane alpha.
#define KP 68
__global__ __launch_bounds__(256, 4) void attn_mfma(const ushort* __restrict__ Qr,
                                                    const ushort* __restrict__ Kr,
                                                    const ushort* __restrict__ Vt,
                                                    ushort* __restrict__ Oa) {
    __shared__ __align__(16) ushort Ksh[64 * KP];
    __shared__ __align__(16) ushort Vsh[64 * KP];
    __shared__ __align__(16) ushort Psh[4][16 * KP];

    const int tid  = threadIdx.x;
    const int lane = tid & 63;
    const int wave = tid >> 6;
    const int quad = lane >> 4;
    const int l16  = lane & 15;
    const int bh   = blockIdx.y;
    const int q0   = ((int)gridDim.x - 1 - (int)blockIdx.x) * 64;  // heavy blocks first
    const long base = (long)bh * (L_SEQ * HDIM);

    // Q A-fragment: lane l16 = q-row (within wave's 16), k = d = ks*32 + quad*8 + j
    bf16x8 qf0, qf1;
    {
        const ushort* qp = Qr + base + (long)(q0 + wave * 16 + l16) * HDIM + quad * 8;
        qf0 = *(const bf16x8*)qp;
        qf1 = *(const bf16x8*)(qp + 32);
    }
    float mrow[4] = {-1e30f, -1e30f, -1e30f, -1e30f};
    float lrow[4] = {0.f, 0.f, 0.f, 0.f};
    f32x4 o[4] = {};

    const int srow  = tid >> 2;        // staging row 0..63
    const int scol  = (tid & 3) * 16;  // 0,16,32,48
    const int row_l = wave * 16 + quad * 4;

    for (int kv0 = 0; kv0 <= q0; kv0 += 64) {
        __syncthreads();
        {   // stage K [kv][d] and V^T [d][kv] tiles
            const ushort* kg = Kr + base + (long)(kv0 + srow) * HDIM + scol;
            uint4 k0v = *(const uint4*)kg;
            uint4 k1v = *(const uint4*)(kg + 8);
            const ushort* vg = Vt + base + (long)srow * L_SEQ + kv0 + scol;
            uint4 v0v = *(const uint4*)vg;
            uint4 v1v = *(const uint4*)(vg + 8);
            *(uint4*)(Ksh + srow * KP + scol)     = k0v;
            *(uint4*)(Ksh + srow * KP + scol + 8) = k1v;
            *(uint4*)(Vsh + srow * KP + scol)     = v0v;
            *(uint4*)(Vsh + srow * KP + scol + 8) = v1v;
        }
        __syncthreads();

        // S = Q K^T  (rows q = row_l + r, cols kv = nt*16 + l16)
        f32x4 s[4] = {};
#pragma unroll
        for (int nt = 0; nt < 4; nt++) {
            bf16x8 kf0 = *(const bf16x8*)(Ksh + (nt * 16 + l16) * KP + quad * 8);
            bf16x8 kf1 = *(const bf16x8*)(Ksh + (nt * 16 + l16) * KP + 32 + quad * 8);
            s[nt] = __builtin_amdgcn_mfma_f32_16x16x32_bf16(qf0, kf0, s[nt], 0, 0, 0);
            s[nt] = __builtin_amdgcn_mfma_f32_16x16x32_bf16(qf1, kf1, s[nt], 0, 0, 0);
        }
        if (kv0 == q0) {  // diagonal tile causal mask
#pragma unroll
            for (int nt = 0; nt < 4; nt++) {
                int col = nt * 16 + l16;
#pragma unroll
                for (int r = 0; r < 4; r++)
                    if (col > row_l + r) s[nt][r] = -1e30f;
            }
        }
        // online softmax per q-row; row spread across 16 lanes of same quad
#pragma unroll
        for (int r = 0; r < 4; r++) {
            float rm = fmaxf(fmaxf(s[0][r], s[1][r]), fmaxf(s[2][r], s[3][r]));
            rm = fmaxf(rm, __shfl_xor(rm, 1));
            rm = fmaxf(rm, __shfl_xor(rm, 2));
            rm = fmaxf(rm, __shfl_xor(rm, 4));
            rm = fmaxf(rm, __shfl_xor(rm, 8));
            float nm = fmaxf(mrow[r], rm);
            float al = __expf(mrow[r] - nm);
            mrow[r] = nm;
            float ps = 0.f;
#pragma unroll
            for (int nt = 0; nt < 4; nt++) {
                float p = __expf(s[nt][r] - nm);
                s[nt][r] = p;
                ps += p;
            }
            ps += __shfl_xor(ps, 1);
            ps += __shfl_xor(ps, 2);
            ps += __shfl_xor(ps, 4);
            ps += __shfl_xor(ps, 8);
            lrow[r] = lrow[r] * al + ps;
#pragma unroll
            for (int nt = 0; nt < 4; nt++) o[nt][r] *= al;
            // C-layout -> LDS (wave-private, no barrier: DS ops wave-ordered)
#pragma unroll
            for (int nt = 0; nt < 4; nt++)
                Psh[wave][(quad * 4 + r) * KP + nt * 16 + l16] = f2bf(s[nt][r]);
        }
        // PV: A = P (A-frag from Psh), B = V^T rows d
#pragma unroll
        for (int ks = 0; ks < 2; ks++) {
            bf16x8 pf = *(const bf16x8*)(&Psh[wave][l16 * KP + ks * 32 + quad * 8]);
#pragma unroll
            for (int nt = 0; nt < 4; nt++) {
                bf16x8 vf = *(const bf16x8*)(Vsh + (nt * 16 + l16) * KP + ks * 32 + quad * 8);
                o[nt] = __builtin_amdgcn_mfma_f32_16x16x32_bf16(pf, vf, o[nt], 0, 0, 0);
            }
        }
    }
    // epilogue: O rows q = row_l + r, cols d = nt*16 + l16 -> Oa[b, l, h*64+d]
    const int b = bh >> 5, h = bh & 31;
#pragma unroll
    for (int r = 0; r < 4; r++) {
        float inv = 1.f / lrow[r];
        long orow = (long)(b * L_SEQ + q0 + wave * 16 + quad * 4 + r) * HID + h * 64;
#pragma unroll
        for (int nt = 0; nt < 4; nt++)
            Oa[orow + nt * 16 + l16] = f2bf(o[nt][r] * inv);
    }
}

// ---------------- host launch ----------------
extern "C" void kernel_launch(void* const* d_in, const int* in_sizes, int n_in,
                              void* d_out, int out_size, void* d_ws, size_t ws_size,
                              hipStream_t stream) {
    const float* hs     = (const float*)d_in[0];
    const float* prev_k = (const float*)d_in[1];
    const float* prev_v = (const float*)d_in[2];
    const float* Wq     = (const float*)d_in[3];
    const float* Wk     = (const float*)d_in[4];
    const float* Wv     = (const float*)d_in[5];
    const float* Wo     = (const float*)d_in[6];
    const float* cosb   = (const float*)d_in[7];
    const float* sinb   = (const float*)d_in[8];
    float* out = (float*)d_out;

    ushort* hs_bf   = (ushort*)d_ws;                 // 2048*2048
    ushort* wqkv_bf = hs_bf + 2048L * 2048;          // 2560*2048
    ushort* wo_bf   = wqkv_bf + 2560L * 2048;        // 2048*2048
    ushort* proj    = wo_bf + 2048L * 2048;          // 2048*2560
    ushort* Qr      = proj + 2048L * 2560;           // 2*32*1024*64
    ushort* Kr      = Qr + 4194304;
    ushort* Vf      = Kr + 4194304;
    ushort* Oa      = Vf + 4194304;                  // 2048*2048
    ushort* Vt      = proj;                          // reuse proj after prep

    cvt_f32_bf16<<<4096, 256, 0, stream>>>(hs, hs_bf, 1048576);
    cvt_f32_bf16<<<4096, 256, 0, stream>>>(Wq, wqkv_bf, 1048576);
    cvt_f32_bf16<<<512, 256, 0, stream>>>(Wk, wqkv_bf + 2048L * 2048, 131072);
    cvt_f32_bf16<<<512, 256, 0, stream>>>(Wv, wqkv_bf + 2304L * 2048, 131072);
    cvt_f32_bf16<<<4096, 256, 0, stream>>>(Wo, wo_bf, 1048576);

    gemm_bt<true><<<dim3(20, 16), 256, 0, stream>>>(hs_bf, wqkv_bf, proj, 2048, 2560, 2048);
    prep_qkv<<<16384, 256, 0, stream>>>(proj, prev_k, prev_v, cosb, sinb, Qr, Kr, Vf);
    vtrans<<<dim3(16, 64), 256, 0, stream>>>(Vf, Vt);
    attn_mfma<<<dim3(16, 64), 256, 0, stream>>>(Qr, Kr, Vt, Oa);
    gemm_bt<false><<<dim3(16, 16), 256, 0, stream>>>(Oa, wo_bf, out, 2048, 2048, 2048);
}

// Round 3
// 276.615 us; speedup vs baseline: 2.0480x; 1.1119x over previous
//
#include <hip/hip_runtime.h>
#include <stdint.h>

#define L_SEQ 1024
#define NHEAD 32
#define NPREV 28
#define HDIM  64
#define HID   2048
#define NPROJ 2560  // 2048 q + 256 k + 256 v

typedef __bf16 bf16_t;
typedef bf16_t bf16x8 __attribute__((ext_vector_type(8)));
typedef float  f32x4  __attribute__((ext_vector_type(4)));

__device__ __forceinline__ ushort f2bf(float x) {
    union { float f; uint32_t u; } v; v.f = x;
    uint32_t r = v.u + 0x7fffu + ((v.u >> 16) & 1u);
    return (ushort)(r >> 16);
}
__device__ __forceinline__ ushort f2bf_t(float x) {  // truncate (cheap, for P in [0,1])
    union { float f; uint32_t u; } v; v.f = x;
    return (ushort)(v.u >> 16);
}
__device__ __forceinline__ float bf2f(ushort u) {
    union { uint32_t u; float f; } v; v.u = ((uint32_t)u) << 16; return v.f;
}
__device__ __forceinline__ void cvt8(float* dst, uint4 u) {
    union { uint32_t u; float f; } t;
    t.u = u.x << 16;         dst[0] = t.f;
    t.u = u.x & 0xffff0000u; dst[1] = t.f;
    t.u = u.y << 16;         dst[2] = t.f;
    t.u = u.y & 0xffff0000u; dst[3] = t.f;
    t.u = u.z << 16;         dst[4] = t.f;
    t.u = u.z & 0xffff0000u; dst[5] = t.f;
    t.u = u.w << 16;         dst[6] = t.f;
    t.u = u.w & 0xffff0000u; dst[7] = t.f;
}

#define GLB(p) ((const __attribute__((address_space(1))) void*)(p))
#define LDS(p) ((__attribute__((address_space(3))) void*)(p))

// ---------------- merged fp32 -> bf16 conversion (5 arrays, 1 dispatch) ----------------
__global__ void cvt_all(const float* __restrict__ s0, const float* __restrict__ s1,
                        const float* __restrict__ s2, const float* __restrict__ s3,
                        const float* __restrict__ s4,
                        ushort* __restrict__ d0, ushort* __restrict__ d1,
                        ushort* __restrict__ d2, ushort* __restrict__ d3,
                        ushort* __restrict__ d4) {
    int blk = blockIdx.x;
    const float* src; ushort* dst; int idx;
    if      (blk < 4096) { src = s0; dst = d0; idx = blk; }
    else if (blk < 8192) { src = s1; dst = d1; idx = blk - 4096; }
    else if (blk < 8704) { src = s2; dst = d2; idx = blk - 8192; }
    else if (blk < 9216) { src = s3; dst = d3; idx = blk - 8704; }
    else                 { src = s4; dst = d4; idx = blk - 9216; }
    int i = idx * 256 + threadIdx.x;
    float4 v = ((const float4*)src)[i];
    ushort4 o;
    o.x = f2bf(v.x); o.y = f2bf(v.y); o.z = f2bf(v.z); o.w = f2bf(v.w);
    ((ushort4*)dst)[i] = o;
}

// ---------------- bf16 GEMM: C[M,N] = A[M,K] * B[N,K]^T ----------------
// 128x128 tile, 4 waves 2x2, global_load_lds width-16, LDS double-buffer,
// SINGLE barrier per K-iter (prefetch issued into buf^1 after barrier).
template <bool OUT_BF16>
__global__ __launch_bounds__(256, 2) void gemm_bt(const ushort* __restrict__ A,
                                                  const ushort* __restrict__ B,
                                                  void* __restrict__ C,
                                                  int M, int N, int K) {
    __shared__ __align__(16) ushort Ash[2 * 128 * 32];
    __shared__ __align__(16) ushort Bsh[2 * 128 * 32];
    const int tid  = threadIdx.x;
    const int lane = tid & 63;
    const int wave = tid >> 6;
    const int quad = lane >> 4;
    const int l16  = lane & 15;
    const int m0 = blockIdx.y * 128;
    const int n0 = blockIdx.x * 128;
    const int wm = (wave >> 1) * 64;
    const int wn = (wave & 1) * 64;

    const int lrow = tid >> 2;        // 0..63
    const int lcol = (tid & 3) * 8;   // 0,8,16,24

    f32x4 acc[4][4] = {};

    const ushort* Ag = A + (long)(m0 + lrow) * K + lcol;
    const ushort* Bg = B + (long)(n0 + lrow) * K + lcol;
    const int woff = wave * 512;

    // preload k0=0 into buf 0
    __builtin_amdgcn_global_load_lds(GLB(Ag),           LDS(Ash + woff),        16, 0, 0);
    __builtin_amdgcn_global_load_lds(GLB(Ag + 64L * K), LDS(Ash + 2048 + woff), 16, 0, 0);
    __builtin_amdgcn_global_load_lds(GLB(Bg),           LDS(Bsh + woff),        16, 0, 0);
    __builtin_amdgcn_global_load_lds(GLB(Bg + 64L * K), LDS(Bsh + 2048 + woff), 16, 0, 0);

    int cur = 0;
    for (int k0 = 0; k0 < K; k0 += 32) {
        __syncthreads();   // drains vmcnt -> buf[cur] ready; all waves done with buf[cur^1]
        if (k0 + 32 < K) {
            const int nb = (cur ^ 1) * 4096;
            __builtin_amdgcn_global_load_lds(GLB(Ag + k0 + 32),           LDS(Ash + nb + woff),        16, 0, 0);
            __builtin_amdgcn_global_load_lds(GLB(Ag + 64L * K + k0 + 32), LDS(Ash + nb + 2048 + woff), 16, 0, 0);
            __builtin_amdgcn_global_load_lds(GLB(Bg + k0 + 32),           LDS(Bsh + nb + woff),        16, 0, 0);
            __builtin_amdgcn_global_load_lds(GLB(Bg + 64L * K + k0 + 32), LDS(Bsh + nb + 2048 + woff), 16, 0, 0);
        }
        const ushort* As = Ash + cur * 4096;
        const ushort* Bs = Bsh + cur * 4096;
        bf16x8 af[4], bf[4];
#pragma unroll
        for (int i = 0; i < 4; i++) {
            af[i] = *(const bf16x8*)(As + (wm + i * 16 + l16) * 32 + quad * 8);
            bf[i] = *(const bf16x8*)(Bs + (wn + i * 16 + l16) * 32 + quad * 8);
        }
#pragma unroll
        for (int mi = 0; mi < 4; mi++)
#pragma unroll
            for (int ni = 0; ni < 4; ni++)
                acc[mi][ni] = __builtin_amdgcn_mfma_f32_16x16x32_bf16(af[mi], bf[ni], acc[mi][ni], 0, 0, 0);
        cur ^= 1;
    }
#pragma unroll
    for (int mi = 0; mi < 4; mi++)
#pragma unroll
        for (int ni = 0; ni < 4; ni++)
#pragma unroll
            for (int r = 0; r < 4; r++) {
                int m = m0 + wm + mi * 16 + quad * 4 + r;
                int n = n0 + wn + ni * 16 + l16;
                float v = acc[mi][ni][r];
                if (OUT_BF16) ((ushort*)C)[(long)m * N + n] = f2bf(v);
                else          ((float*)C)[(long)m * N + n]  = v;
            }
}

// ---------------- prep: DeCAN gather + RoPE + V transpose fused ----------------
// grid (16 l-tiles, 64 bh). Each block: 64 l x 64 d.
// Q scaled by 0.125*log2(e) so attention softmax can use exp2 directly.
__global__ __launch_bounds__(256) void prep_qkv(const ushort* __restrict__ proj,
                                                const float* __restrict__ prev_k,
                                                const float* __restrict__ prev_v,
                                                const float* __restrict__ cosb,
                                                const float* __restrict__ sinb,
                                                ushort* __restrict__ Qr,
                                                ushort* __restrict__ Kr,
                                                ushort* __restrict__ Vt) {
    __shared__ __align__(16) ushort T[64 * 72];  // V^T tile
    const int t  = threadIdx.x;
    const int l0 = blockIdx.x * 64;
    const int bh = blockIdx.y;
    const int b  = bh >> 5, h = bh & 31;
    const int r  = t >> 2;          // local l row
    const int c0 = (t & 3) * 8;     // d base in [0,32)
    const int l  = l0 + r;
    const long prow = ((long)(b * L_SEQ + l)) * NPROJ;
    const long base = (long)bh * (L_SEQ * HDIM);

    float cv[8], sv[8];
    *(float4*)(cv)     = *(const float4*)(cosb + l * 64 + c0);
    *(float4*)(cv + 4) = *(const float4*)(cosb + l * 64 + c0 + 4);
    *(float4*)(sv)     = *(const float4*)(sinb + l * 64 + c0);
    *(float4*)(sv + 4) = *(const float4*)(sinb + l * 64 + c0 + 4);

    const float SC = 0.125f * 1.44269504f;  // scale * log2(e)

    // ---- Q ----
    {
        float xl[8], xh[8];
        cvt8(xl, *(const uint4*)(proj + prow + h * 64 + c0));
        cvt8(xh, *(const uint4*)(proj + prow + h * 64 + c0 + 32));
        ushort ol[8], oh[8];
#pragma unroll
        for (int i = 0; i < 8; i++) {
            ol[i] = f2bf((xl[i] * cv[i] - xh[i] * sv[i]) * SC);
            oh[i] = f2bf((xh[i] * cv[i] + xl[i] * sv[i]) * SC);
        }
        ushort* q = Qr + base + (long)l * 64;
        *(uint4*)(q + c0)      = *(uint4*)ol;
        *(uint4*)(q + c0 + 32) = *(uint4*)oh;
    }
    // ---- K ----
    {
        float xl[8], xh[8];
        if (h < NPREV) {
            const float* pk = prev_k + (((long)b * NPREV + h) * L_SEQ + l) * 64;
            *(float4*)(xl)     = *(const float4*)(pk + c0);
            *(float4*)(xl + 4) = *(const float4*)(pk + c0 + 4);
            *(float4*)(xh)     = *(const float4*)(pk + c0 + 32);
            *(float4*)(xh + 4) = *(const float4*)(pk + c0 + 36);
        } else {
            cvt8(xl, *(const uint4*)(proj + prow + HID + (h - NPREV) * 64 + c0));
            cvt8(xh, *(const uint4*)(proj + prow + HID + (h - NPREV) * 64 + c0 + 32));
        }
        ushort ol[8], oh[8];
#pragma unroll
        for (int i = 0; i < 8; i++) {
            ol[i] = f2bf(xl[i] * cv[i] - xh[i] * sv[i]);
            oh[i] = f2bf(xh[i] * cv[i] + xl[i] * sv[i]);
        }
        ushort* k = Kr + base + (long)l * 64;
        *(uint4*)(k + c0)      = *(uint4*)ol;
        *(uint4*)(k + c0 + 32) = *(uint4*)oh;
    }
    // ---- V (transpose via LDS) ----
    {
        float xl[8], xh[8];
        if (h < NPREV) {
            const float* pv = prev_v + (((long)b * NPREV + h) * L_SEQ + l) * 64;
            *(float4*)(xl)     = *(const float4*)(pv + c0);
            *(float4*)(xl + 4) = *(const float4*)(pv + c0 + 4);
            *(float4*)(xh)     = *(const float4*)(pv + c0 + 32);
            *(float4*)(xh + 4) = *(const float4*)(pv + c0 + 36);
        } else {
            cvt8(xl, *(const uint4*)(proj + prow + HID + 256 + (h - NPREV) * 64 + c0));
            cvt8(xh, *(const uint4*)(proj + prow + HID + 256 + (h - NPREV) * 64 + c0 + 32));
        }
#pragma unroll
        for (int i = 0; i < 8; i++) {
            T[(c0 + i) * 72 + r]      = f2bf(xl[i]);
            T[(c0 + 32 + i) * 72 + r] = f2bf(xh[i]);
        }
    }
    __syncthreads();
    {   // row d = r, 16 l-cols
        const int lc = (t & 3) * 16;
        uint4 o0 = *(const uint4*)(T + r * 72 + lc);
        uint4 o1 = *(const uint4*)(T + r * 72 + lc + 8);
        ushort* og = Vt + base + (long)r * L_SEQ + l0 + lc;
        *(uint4*)og       = o0;
        *(uint4*)(og + 8) = o1;
    }
}

// ---------------- MFMA flash attention (prefetch-pipelined) ----------------
#define KP 68
__global__ __launch_bounds__(256, 4) void attn_mfma(const ushort* __restrict__ Qr,
                                                    const ushort* __restrict__ Kr,
                                                    const ushort* __restrict__ Vt,
                                                    ushort* __restrict__ Oa) {
    __shared__ __align__(16) ushort Ksh[64 * KP];
    __shared__ __align__(16) ushort Vsh[64 * KP];
    __shared__ __align__(16) ushort Psh[4][16 * KP];

    const int tid  = threadIdx.x;
    const int lane = tid & 63;
    const int wave = tid >> 6;
    const int quad = lane >> 4;
    const int l16  = lane & 15;
    const int bh   = blockIdx.y;
    const int q0   = (15 - (int)blockIdx.x) * 64;  // heavy blocks first
    const long base = (long)bh * (L_SEQ * HDIM);

    bf16x8 qf0, qf1;
    {
        const ushort* qp = Qr + base + (long)(q0 + wave * 16 + l16) * HDIM + quad * 8;
        qf0 = *(const bf16x8*)qp;
        qf1 = *(const bf16x8*)(qp + 32);
    }
    float mrow[4] = {-1e30f, -1e30f, -1e30f, -1e30f};
    float lrow[4] = {0.f, 0.f, 0.f, 0.f};   // per-lane partial sums
    f32x4 o[4] = {};

    const int srow  = tid >> 2;
    const int scol  = (tid & 3) * 16;
    const int row_l = wave * 16 + quad * 4;

    // prefetch tile 0
    uint4 ka, kb, va, vb;
    {
        const ushort* kg = Kr + base + (long)srow * HDIM + scol;
        ka = *(const uint4*)kg; kb = *(const uint4*)(kg + 8);
        const ushort* vg = Vt + base + (long)srow * L_SEQ + scol;
        va = *(const uint4*)vg; vb = *(const uint4*)(vg + 8);
    }

    for (int kv0 = 0; kv0 <= q0; kv0 += 64) {
        __syncthreads();
        *(uint4*)(Ksh + srow * KP + scol)     = ka;
        *(uint4*)(Ksh + srow * KP + scol + 8) = kb;
        *(uint4*)(Vsh + srow * KP + scol)     = va;
        *(uint4*)(Vsh + srow * KP + scol + 8) = vb;
        __syncthreads();
        if (kv0 + 64 <= q0) {   // prefetch next tile; latency hidden by compute
            const ushort* kg = Kr + base + (long)(kv0 + 64 + srow) * HDIM + scol;
            ka = *(const uint4*)kg; kb = *(const uint4*)(kg + 8);
            const ushort* vg = Vt + base + (long)srow * L_SEQ + kv0 + 64 + scol;
            va = *(const uint4*)vg; vb = *(const uint4*)(vg + 8);
        }

        // S = Q K^T
        f32x4 s[4] = {};
#pragma unroll
        for (int nt = 0; nt < 4; nt++) {
            bf16x8 kf0 = *(const bf16x8*)(Ksh + (nt * 16 + l16) * KP + quad * 8);
            bf16x8 kf1 = *(const bf16x8*)(Ksh + (nt * 16 + l16) * KP + 32 + quad * 8);
            s[nt] = __builtin_amdgcn_mfma_f32_16x16x32_bf16(qf0, kf0, s[nt], 0, 0, 0);
            s[nt] = __builtin_amdgcn_mfma_f32_16x16x32_bf16(qf1, kf1, s[nt], 0, 0, 0);
        }
        if (kv0 == q0) {
#pragma unroll
            for (int nt = 0; nt < 4; nt++) {
                int col = nt * 16 + l16;
#pragma unroll
                for (int r = 0; r < 4; r++)
                    if (col > row_l + r) s[nt][r] = -1e30f;
            }
        }
        // online softmax (scores already in log2 units)
#pragma unroll
        for (int r = 0; r < 4; r++) {
            float rm = fmaxf(fmaxf(s[0][r], s[1][r]), fmaxf(s[2][r], s[3][r]));
            rm = fmaxf(rm, __shfl_xor(rm, 1));
            rm = fmaxf(rm, __shfl_xor(rm, 2));
            rm = fmaxf(rm, __shfl_xor(rm, 4));
            rm = fmaxf(rm, __shfl_xor(rm, 8));
            float nm = fmaxf(mrow[r], rm);
            float al = __builtin_exp2f(mrow[r] - nm);
            mrow[r] = nm;
            float ps = 0.f;
#pragma unroll
            for (int nt = 0; nt < 4; nt++) {
                float p = __builtin_exp2f(s[nt][r] - nm);
                ps += p;
                Psh[wave][(quad * 4 + r) * KP + nt * 16 + l16] = f2bf_t(p);
            }
            lrow[r] = lrow[r] * al + ps;   // per-lane partial; reduce at end
#pragma unroll
            for (int nt = 0; nt < 4; nt++) o[nt][r] *= al;
        }
        // PV
#pragma unroll
        for (int ks = 0; ks < 2; ks++) {
            bf16x8 pf = *(const bf16x8*)(&Psh[wave][l16 * KP + ks * 32 + quad * 8]);
#pragma unroll
            for (int nt = 0; nt < 4; nt++) {
                bf16x8 vf = *(const bf16x8*)(Vsh + (nt * 16 + l16) * KP + ks * 32 + quad * 8);
                o[nt] = __builtin_amdgcn_mfma_f32_16x16x32_bf16(pf, vf, o[nt], 0, 0, 0);
            }
        }
    }
    // epilogue: reduce l across the 16 lanes sharing each row, then write
    const int b = bh >> 5, h = bh & 31;
#pragma unroll
    for (int r = 0; r < 4; r++) {
        float lr = lrow[r];
        lr += __shfl_xor(lr, 1);
        lr += __shfl_xor(lr, 2);
        lr += __shfl_xor(lr, 4);
        lr += __shfl_xor(lr, 8);
        float inv = 1.f / lr;
        long orow = (long)(b * L_SEQ + q0 + wave * 16 + quad * 4 + r) * HID + h * 64;
#pragma unroll
        for (int nt = 0; nt < 4; nt++)
            Oa[orow + nt * 16 + l16] = f2bf(o[nt][r] * inv);
    }
}

// ---------------- host launch ----------------
extern "C" void kernel_launch(void* const* d_in, const int* in_sizes, int n_in,
                              void* d_out, int out_size, void* d_ws, size_t ws_size,
                              hipStream_t stream) {
    const float* hs     = (const float*)d_in[0];
    const float* prev_k = (const float*)d_in[1];
    const float* prev_v = (const float*)d_in[2];
    const float* Wq     = (const float*)d_in[3];
    const float* Wk     = (const float*)d_in[4];
    const float* Wv     = (const float*)d_in[5];
    const float* Wo     = (const float*)d_in[6];
    const float* cosb   = (const float*)d_in[7];
    const float* sinb   = (const float*)d_in[8];
    float* out = (float*)d_out;

    ushort* hs_bf   = (ushort*)d_ws;                 // 2048*2048
    ushort* wqkv_bf = hs_bf + 2048L * 2048;          // 2560*2048
    ushort* wo_bf   = wqkv_bf + 2560L * 2048;        // 2048*2048
    ushort* proj    = wo_bf + 2048L * 2048;          // 2048*2560
    ushort* Qr      = proj + 2048L * 2560;           // 2*32*1024*64
    ushort* Kr      = Qr + 4194304;
    ushort* Vt      = Kr + 4194304;
    ushort* Oa      = Vt + 4194304;                  // 2048*2048

    cvt_all<<<13312, 256, 0, stream>>>(hs, Wq, Wk, Wv, Wo,
                                       hs_bf, wqkv_bf,
                                       wqkv_bf + 2048L * 2048,
                                       wqkv_bf + 2304L * 2048,
                                       wo_bf);
    gemm_bt<true><<<dim3(20, 16), 256, 0, stream>>>(hs_bf, wqkv_bf, proj, 2048, 2560, 2048);
    prep_qkv<<<dim3(16, 64), 256, 0, stream>>>(proj, prev_k, prev_v, cosb, sinb, Qr, Kr, Vt);
    attn_mfma<<<dim3(16, 64), 256, 0, stream>>>(Qr, Kr, Vt, Oa);
    gemm_bt<false><<<dim3(16, 16), 256, 0, stream>>>(Oa, wo_bf, out, 2048, 2048, 2048);
}